// Round 12
// baseline (28313.483 us; speedup 1.0000x reference)
//
#include <hip/hip_runtime.h>
#include <stdint.h>
#include <stddef.h>

// GRU (B=32, T=2048, I=H=512, fp32 in/out).
// Phase 1 (MFMA GEMM): gz|gr -> fp16 INTO d_out (row-aliased); gh -> d_ws.
// Phase 2 (R12): MFMA-batched persistent scan. 32 WGs = 2 groups x 16 slices.
//   Group = 16 batches (M=16 MFMA tile); slice = 32 hidden cols.
//   Weights LDS-resident, read ONCE per step for 16 batch-steps (R8 spent the
//   same LDS BW per single batch-step). Exchange = thin tagged-u32 rh/h
//   gathers (agent scope only: R9/R10 proved consumer-cacheable polls
//   livelock). z/htil stay lane-local (same MFMA C-layout for both).
// Fallback (!gh_mode): R8 scalar scan.

#define AGENT __HIP_MEMORY_SCOPE_AGENT

typedef _Float16 h2v __attribute__((ext_vector_type(2)));
typedef _Float16 half8 __attribute__((ext_vector_type(8)));
typedef float f32x4 __attribute__((ext_vector_type(4)));

__device__ __forceinline__ uint32_t pk2u(float a, float b) {
  h2v r; r[0] = (_Float16)a; r[1] = (_Float16)b;
  return __builtin_bit_cast(uint32_t, r);
}
__device__ __forceinline__ h2v bc2(uint32_t u) { return __builtin_bit_cast(h2v, u); }
__device__ __forceinline__ float dot2f(h2v a, h2v b, float c) {
#if __has_builtin(__builtin_amdgcn_fdot2)
  return __builtin_amdgcn_fdot2(a, b, c, false);
#else
  return fmaf((float)a[1], (float)b[1], fmaf((float)a[0], (float)b[0], c));
#endif
}
__device__ __forceinline__ float sigmoidf_(float x) { return 1.0f / (1.0f + __expf(-x)); }
__device__ __forceinline__ float tanhf_(float x) { return 1.0f - 2.0f / (1.0f + __expf(2.0f * x)); }

__device__ __forceinline__ uint32_t ald32(const uint32_t* p) {
  return __hip_atomic_load(p, __ATOMIC_RELAXED, AGENT);
}
__device__ __forceinline__ void ast32(uint32_t* p, uint32_t v) {
  __hip_atomic_store(p, v, __ATOMIC_RELAXED, AGENT);
}
__device__ __forceinline__ uint64_t ald64(const uint64_t* p) {
  return __hip_atomic_load(p, __ATOMIC_RELAXED, AGENT);
}
__device__ __forceinline__ void ast64(uint64_t* p, uint64_t v) {
  __hip_atomic_store(p, v, __ATOMIC_RELAXED, AGENT);
}

// ---------------- Phase 1: gate GEMM  [65536 x 512] @ [512 x N*128] -> fp16 ----------------
__global__ __launch_bounds__(256) void gemm_gx(const float* __restrict__ x,
                                               const float* __restrict__ Wx,
                                               const float* __restrict__ bias,
                                               _Float16* gzr,   // [65536][1024] (aliases out)
                                               _Float16* gh,    // [65536][512] in ws (opt)
                                               int nTN) {
  __shared__ alignas(16) _Float16 Alds[128 * 68];
  __shared__ alignas(16) _Float16 Blds[128 * 68];
  const int tid = threadIdx.x;
  const int bid = blockIdx.x;
  const int tm = bid / nTN, tn = bid % nTN;
  const int m0 = tm << 7, n0 = tn << 7;
  const int lane = tid & 63;
  const int wv = tid >> 6, wm = wv >> 1, wn = wv & 1;
  const int l15 = lane & 15, lhi = lane >> 4;
  f32x4 acc[4][4] = {};

  for (int k0 = 0; k0 < 512; k0 += 64) {
#pragma unroll
    for (int r = 0; r < 8; ++r) {
      int m = r * 16 + (tid >> 4);
      int k = (tid & 15) * 4;
      float4 v = *(const float4*)&x[(size_t)(m0 + m) * 512 + k0 + k];
      union { _Float16 h[4]; uint2 u; } cv;
      cv.h[0] = (_Float16)v.x; cv.h[1] = (_Float16)v.y;
      cv.h[2] = (_Float16)v.z; cv.h[3] = (_Float16)v.w;
      *(uint2*)&Alds[m * 68 + k] = cv.u;
    }
#pragma unroll
    for (int u = 0; u < 8; ++u) {
      int n = tid & 127;
      int k = (tid >> 7) * 32 + u * 4;
      int ng = n0 + n;
      const float* wp = Wx + ((size_t)(ng >> 9) << 18) + (size_t)(k0 + k) * 512 + (ng & 511);
      union { _Float16 h[4]; uint2 u2; } cv;
      cv.h[0] = (_Float16)wp[0];    cv.h[1] = (_Float16)wp[512];
      cv.h[2] = (_Float16)wp[1024]; cv.h[3] = (_Float16)wp[1536];
      *(uint2*)&Blds[n * 68 + k] = cv.u2;
    }
    __syncthreads();
#pragma unroll
    for (int kk = 0; kk < 2; ++kk) {
      int q = kk * 4 + lhi;
      half8 af[4], bf[4];
#pragma unroll
      for (int fm = 0; fm < 4; ++fm) {
        const _Float16* pa = &Alds[(wm * 64 + fm * 16 + l15) * 68 + q * 8];
        union { uint2 u[2]; half8 h; } cv;
        cv.u[0] = *(const uint2*)pa; cv.u[1] = *(const uint2*)(pa + 4);
        af[fm] = cv.h;
      }
#pragma unroll
      for (int fn = 0; fn < 4; ++fn) {
        const _Float16* pb = &Blds[(wn * 64 + fn * 16 + l15) * 68 + q * 8];
        union { uint2 u[2]; half8 h; } cv;
        cv.u[0] = *(const uint2*)pb; cv.u[1] = *(const uint2*)(pb + 4);
        bf[fn] = cv.h;
      }
#pragma unroll
      for (int fm = 0; fm < 4; ++fm)
#pragma unroll
        for (int fn = 0; fn < 4; ++fn)
          acc[fm][fn] = __builtin_amdgcn_mfma_f32_16x16x32_f16(af[fm], bf[fn], acc[fm][fn], 0, 0, 0);
    }
    __syncthreads();
  }
#pragma unroll
  for (int fn = 0; fn < 4; ++fn) {
    int col = n0 + wn * 64 + fn * 16 + l15;
    float bv = bias[col];
#pragma unroll
    for (int fm = 0; fm < 4; ++fm) {
#pragma unroll
      for (int q2 = 0; q2 < 4; ++q2) {
        int row = m0 + wm * 64 + fm * 16 + lhi * 4 + q2;
        _Float16 val = (_Float16)(acc[fm][fn][q2] + bv);
        if (n0 < 1024) gzr[(size_t)row * 1024 + col] = val;
        else           gh[(size_t)row * 512 + (col - 1024)] = val;
      }
    }
  }
}

// ---------------- Phase 2 (R12): MFMA-batched persistent scan ----------------
// Gather 16 consecutive tagged u32 words, write fp16 payloads into LDS.
__device__ __forceinline__ void gather16(const uint32_t* base, uint32_t want,
                                         _Float16* dst) {
  uint32_t w[16];
#pragma unroll
  for (int j = 0; j < 16; ++j) w[j] = ald32(base + j);
  for (;;) {
    bool ok = true;
#pragma unroll
    for (int j = 0; j < 16; ++j) ok &= ((w[j] >> 16) == want);
    if (ok) break;
    __builtin_amdgcn_s_sleep(1);
#pragma unroll
    for (int j = 0; j < 16; ++j)
      if ((w[j] >> 16) != want) w[j] = ald32(base + j);
  }
  uint32_t* d32 = (uint32_t*)dst;
#pragma unroll
  for (int j = 0; j < 8; ++j)
    d32[j] = (w[2 * j] & 0xffffu) | (w[2 * j + 1] << 16);
}

__global__ __launch_bounds__(512) void gru_scan_mfma(
    const _Float16* gzr,            // [65536][1024] (aliases out!)
    const _Float16* ghg,            // [65536][512]
    const float* __restrict__ Wh,   // [3][512][512]
    float* out,                     // [32][2048][512] + [32][512]
    uint32_t* __restrict__ rhbuf,   // [2 grp][16 b][512 col] tagged u32
    uint32_t* __restrict__ hbuf) {  // same
  // stride 520 halves: 1040 B rows -> 16B-aligned b128 frags, ~2-way banks
  __shared__ alignas(16) _Float16 wzr[64 * 520];   // [z c0..31 | r c0..31][k]
  __shared__ alignas(16) _Float16 whh[32 * 520];   // [c][k]
  __shared__ alignas(16) _Float16 hA[16 * 520];    // [batch][k] = h_{t-1}
  __shared__ alignas(16) _Float16 rhA[16 * 520];   // [batch][k] = r*h
  __shared__ alignas(16) float pP[2 * 64 * 20];    // zr partials; reused as [4][32][20] for cand
  __shared__ alignas(16) _Float16 gzS[16][32], grS[16][32], ghS[16][32];

  const int tid = threadIdx.x;
  const int bid = blockIdx.x;      // 0..31
  const int g = bid >> 4;          // group: batches [g*16, g*16+16)
  const int s = bid & 15;          // slice: cols [s*32, s*32+32)
  const int c0 = s * 32;
  const int bb = g * 16;
  const int lane = tid & 63, wv = tid >> 6;
  const int l15 = lane & 15, lhi = lane >> 4;
  const int b = tid >> 5, c = tid & 31;  // reduce/update identity: (batch, col)

  // ---- weight fill (once): wzr/whh [col][k] = W[k][c0+col] ----
  {
    const int cc = tid & 31, kb = tid >> 5;
#pragma unroll 8
    for (int i = 0; i < 32; ++i) {
      int k = kb * 32 + i;
      wzr[cc * 520 + k]        = (_Float16)Wh[(size_t)k * 512 + c0 + cc];
      wzr[(32 + cc) * 520 + k] = (_Float16)Wh[262144 + (size_t)k * 512 + c0 + cc];
      whh[cc * 520 + k]        = (_Float16)Wh[524288 + (size_t)k * 512 + c0 + cc];
    }
  }
  for (int i = tid; i < 16 * 520; i += 512) hA[i] = (_Float16)0.0f;

  // prefetch gates row 0
  _Float16 gz_p, gr_p, gh_p;
  {
    size_t r0 = (size_t)(bb + b) * 2048;
    gz_p = gzr[r0 * 1024 + c0 + c];
    gr_p = gzr[r0 * 1024 + 512 + c0 + c];
    gh_p = ghg[r0 * 512 + c0 + c];
  }

  uint32_t* rhb = rhbuf + (size_t)g * 8192;
  uint32_t* hb  = hbuf + (size_t)g * 8192;
  const int gw = tid * 16;                 // this thread's gather window (flat b*512+col)
  const int gwb = gw >> 9, gwc = gw & 511;

  for (int t = 0; t < 2048; ++t) {
    __syncthreads();  // guards gate-LDS & pP vs previous phase-6 reads
    // ---- phase 1: stage gates; gather h(t-1) ----
    gzS[b][c] = gz_p; grS[b][c] = gr_p; ghS[b][c] = gh_p;
    if (t > 0)
      gather16(hb + gw, (uint32_t)t, &hA[gwb * 520 + gwc]);
    __syncthreads();  // hA + gates ready

    // ---- phase 2: z/r MFMA  [16b x 512k] @ [512k x 64(z|r)] ----
    {
      const int nt = wv >> 1, kh = wv & 1;
      f32x4 acc = {};
#pragma unroll
      for (int i = 0; i < 8; ++i) {
        int kc = kh * 8 + i;
        half8 a = *(const half8*)&hA[l15 * 520 + kc * 32 + lhi * 8];
        half8 bf = *(const half8*)&wzr[(nt * 16 + l15) * 520 + kc * 32 + lhi * 8];
        acc = __builtin_amdgcn_mfma_f32_16x16x32_f16(a, bf, acc, 0, 0, 0);
      }
      *(f32x4*)&pP[(kh * 64 + nt * 16 + l15) * 20 + lhi * 4] = acc;
    }
    if (t < 2047) {  // prefetch gates t+1 (hidden under MFMA)
      size_t r1 = (size_t)(bb + b) * 2048 + t + 1;
      gz_p = gzr[r1 * 1024 + c0 + c];
      gr_p = gzr[r1 * 1024 + 512 + c0 + c];
      gh_p = ghg[r1 * 512 + c0 + c];
    }
    __syncthreads();  // pP(zr) complete

    // ---- phase 3: reduce z/r, rh, publish rh ----
    float zp = pP[(c)*20 + b] + pP[(64 + c) * 20 + b];
    float rp = pP[(32 + c) * 20 + b] + pP[(96 + c) * 20 + b];
    float z = sigmoidf_(zp + (float)gzS[b][c]);
    float r = sigmoidf_(rp + (float)grS[b][c]);
    float hold = (float)hA[b * 520 + c0 + c];
    _Float16 rh16 = (_Float16)(r * hold);
    rhA[b * 520 + c0 + c] = rh16;
    ast32(rhb + b * 512 + c0 + c,
          ((uint32_t)(t + 1) << 16) | (uint32_t)__builtin_bit_cast(unsigned short, rh16));

    // ---- phase 4: gather full rh ----
    gather16(rhb + gw, (uint32_t)(t + 1), &rhA[gwb * 520 + gwc]);
    __syncthreads();  // rhA complete; phase-3 pP reads all done

    // ---- phase 5: candidate MFMA  [16b x 512k] @ [512k x 32c] ----
    {
      const int nt = wv >> 2, kq = wv & 3;
      f32x4 acc = {};
#pragma unroll
      for (int i = 0; i < 4; ++i) {
        int kc = kq * 4 + i;
        half8 a = *(const half8*)&rhA[l15 * 520 + kc * 32 + lhi * 8];
        half8 bf = *(const half8*)&whh[(nt * 16 + l15) * 520 + kc * 32 + lhi * 8];
        acc = __builtin_amdgcn_mfma_f32_16x16x32_f16(a, bf, acc, 0, 0, 0);
      }
      *(f32x4*)&pP[(kq * 32 + nt * 16 + l15) * 20 + lhi * 4] = acc;
    }
    __syncthreads();  // pP(cand) complete

    // ---- phase 6: reduce cand, h-update, out, publish h ----
    {
      float hp = pP[(c)*20 + b] + pP[(32 + c) * 20 + b] +
                 pP[(64 + c) * 20 + b] + pP[(96 + c) * 20 + b];
      float htil = tanhf_(hp + (float)ghS[b][c]);
      float hn = fmaf(z, htil - hold, hold);
      out[((size_t)(bb + b) * 2048 + t) * 512 + c0 + c] = hn;
      _Float16 h16v = (_Float16)hn;
      hA[b * 520 + c0 + c] = h16v;
      ast32(hb + b * 512 + c0 + c,
            ((uint32_t)(t + 1) << 16) | (uint32_t)__builtin_bit_cast(unsigned short, h16v));
      if (t == 2047)
        out[(size_t)32 * 2048 * 512 + (size_t)(bb + b) * 512 + c0 + c] = hn;
    }
  }
}

// ---------------- Fallback scan (R8 scalar, GH=false path) ----------------
template <bool GH>
__global__ __launch_bounds__(512) void gru_scan_fb(
    const float* __restrict__ x, const float* __restrict__ Wx,
    const float* __restrict__ Wh, const float* __restrict__ bias,
    const _Float16* gzr, const _Float16* gh, float* out,
    uint64_t* __restrict__ Pbuf, uint64_t* __restrict__ zbuf) {
  __shared__ alignas(16) float zrp[2][8][64];
  __shared__ alignas(16) _Float16 wzrL[2 * 64 * 516];
  __shared__ alignas(16) _Float16 h16[512];
  __shared__ alignas(16) _Float16 rh16[64];
  __shared__ alignas(16) _Float16 x16s[64];

  const int T = threadIdx.x;
  const int bid = blockIdx.x;
  const int xcd = bid & 7, ii = bid >> 3;
  const int batch = xcd * 4 + (ii >> 3);
  const int slice = ii & 7;
  const int wv = T >> 6, ln = T & 63, n = T;
  {
    const int cc = T & 63, kb = T >> 6;
#pragma unroll 4
    for (int g = 0; g < 2; ++g) {
      const float* W = Wh + (size_t)g * 262144 + slice * 64 + cc;
      for (int i = 0; i < 64; ++i) {
        int k = kb + 8 * i;
        wzrL[(g * 64 + cc) * 516 + k] = (_Float16)W[(size_t)k * 512];
      }
    }
  }
  uint32_t wh2[32], wx2[32];
  {
    const float* Whh = Wh + 524288;
    const float* Wxh = Wx + 524288;
#pragma unroll
    for (int j = 0; j < 32; ++j) {
      int kk = slice * 64 + 2 * j;
      wh2[j] = pk2u(Whh[(size_t)kk * 512 + n], Whh[(size_t)(kk + 1) * 512 + n]);
      wx2[j] = pk2u(Wxh[(size_t)kk * 512 + n], Wxh[(size_t)(kk + 1) * 512 + n]);
    }
  }
  const float bh = bias[1024 + n];
  float hreg = 0.0f;
  h16[T] = (_Float16)0.0f;
  const size_t rowbase = (size_t)batch * 2048;
  float gz_p = 0.f, gr_p = 0.f, gz_cur = 0.f, gr_cur = 0.f, x_p = 0.f;
  if (T < 64)       gz_p = (float)gzr[rowbase * 1024 + slice * 64 + T];
  else if (T < 128) gr_p = (float)gzr[rowbase * 1024 + 512 + slice * 64 + (T - 64)];
  if (T < 64) x_p = x[rowbase * 512 + slice * 64 + T];

  uint64_t* Pmine = Pbuf + ((size_t)batch * 8 + slice) * 512 + n;
  const uint64_t* Pread = Pbuf + ((size_t)batch * 8) * 512 + n;
  uint64_t* zmine = zbuf + (size_t)batch * 512 + slice * 64 + ln;
  const uint64_t* zread = zbuf + (size_t)batch * 512 + n;

  for (int t = 0; t < 2048; ++t) {
    if (t > 0) {
      const size_t po = ((t - 1) & 1) ? 131072 : 0;
      const size_t zo = ((t - 1) & 1) ? 16384 : 0;
      const uint32_t want = (uint32_t)t;
      uint64_t v[8];
#pragma unroll
      for (int g = 0; g < 8; ++g) v[g] = ald64(Pread + po + (size_t)g * 512);
      uint64_t zv = ald64(zread + zo);
      for (;;) {
        bool ok = true;
        if ((uint32_t)(zv >> 32) != want) { zv = ald64(zread + zo); ok = false; }
#pragma unroll
        for (int g = 0; g < 8; ++g)
          if ((uint32_t)(v[g] >> 32) != want) { v[g] = ald64(Pread + po + (size_t)g * 512); ok = false; }
        if (ok) break;
        __builtin_amdgcn_s_sleep(1);
      }
      float hsum = 0.f;
#pragma unroll
      for (int g = 0; g < 8; ++g) hsum += __uint_as_float((uint32_t)v[g]);
      float zf = __uint_as_float((uint32_t)zv);
      float htil = tanhf_(bh + hsum);
      float hn = fmaf(zf, htil - hreg, hreg);
      if (slice == 0) out[(rowbase + (t - 1)) * 512 + n] = hn;
      hreg = hn;
      h16[T] = (_Float16)hn;
    }
    gz_cur = gz_p; gr_cur = gr_p;
    if (T < 64) x16s[T] = (_Float16)x_p;
    __syncthreads();
    if (t < 2047) {
      size_t r1 = rowbase + t + 1;
      if (T < 64)       gz_p = (float)gzr[r1 * 1024 + slice * 64 + T];
      else if (T < 128) gr_p = (float)gzr[r1 * 1024 + 512 + slice * 64 + (T - 64)];
      if (T < 64) x_p = x[r1 * 512 + slice * 64 + T];
    }
    float za = 0.f, ra = 0.f;
    {
      const _Float16* wzp = &wzrL[ln * 516 + 64 * wv];
      const _Float16* wrp = &wzrL[(64 + ln) * 516 + 64 * wv];
      const _Float16* hp = &h16[64 * wv];
#pragma unroll
      for (int j = 0; j < 16; ++j) {
        uint2 wzu = *(const uint2*)(wzp + 4 * j);
        uint2 wru = *(const uint2*)(wrp + 4 * j);
        uint2 hu = *(const uint2*)(hp + 4 * j);
        za = dot2f(bc2(hu.x), bc2(wzu.x), za);
        za = dot2f(bc2(hu.y), bc2(wzu.y), za);
        ra = dot2f(bc2(hu.x), bc2(wru.x), ra);
        ra = dot2f(bc2(hu.y), bc2(wru.y), ra);
      }
    }
    zrp[0][wv][ln] = za;
    zrp[1][wv][ln] = ra;
    __syncthreads();
    const size_t po = (t & 1) ? 131072 : 0;
    const size_t zo = (t & 1) ? 16384 : 0;
    const uint64_t tagw = ((uint64_t)(uint32_t)(t + 1)) << 32;
    if (T < 128) {
      const int g = T >> 6, cc = T & 63;
      float sum = 0.f;
#pragma unroll
      for (int s2 = 0; s2 < 8; ++s2) sum += zrp[g][s2][cc];
      if (g == 0) {
        float z = sigmoidf_(sum + gz_cur);
        ast64(zmine + zo, tagw | (uint32_t)__float_as_uint(z));
      } else {
        float r = sigmoidf_(sum + gr_cur);
        rh16[cc] = (_Float16)(r * (float)h16[slice * 64 + cc]);
      }
    }
    __syncthreads();
    float pa = 0.f;
#pragma unroll
    for (int j = 0; j < 16; ++j) {
      uint2 ru = *(const uint2*)&rh16[4 * j];
      pa = dot2f(bc2(ru.x), bc2(wh2[2 * j]), pa);
      pa = dot2f(bc2(ru.y), bc2(wh2[2 * j + 1]), pa);
    }
#pragma unroll
    for (int j = 0; j < 16; ++j) {
      uint2 xu = *(const uint2*)&x16s[4 * j];
      pa = dot2f(bc2(xu.x), bc2(wx2[2 * j]), pa);
      pa = dot2f(bc2(xu.y), bc2(wx2[2 * j + 1]), pa);
    }
    ast64(Pmine + po, tagw | (uint32_t)__float_as_uint(pa));
    __syncthreads();
  }
  {
    const uint32_t want = 2048u;
    uint64_t v[8];
#pragma unroll
    for (int g = 0; g < 8; ++g) v[g] = ald64(Pread + 131072 + (size_t)g * 512);
    uint64_t zv = ald64(zread + 16384);
    for (;;) {
      bool ok = true;
      if ((uint32_t)(zv >> 32) != want) { zv = ald64(zread + 16384); ok = false; }
#pragma unroll
      for (int g = 0; g < 8; ++g)
        if ((uint32_t)(v[g] >> 32) != want) { v[g] = ald64(Pread + 131072 + (size_t)g * 512); ok = false; }
      if (ok) break;
      __builtin_amdgcn_s_sleep(1);
    }
    float hsum = 0.f;
#pragma unroll
    for (int g = 0; g < 8; ++g) hsum += __uint_as_float((uint32_t)v[g]);
    float zf = __uint_as_float((uint32_t)zv);
    float htil = tanhf_(bh + hsum);
    float hn = fmaf(zf, htil - hreg, hreg);
    if (slice == 0) {
      out[(rowbase + 2047) * 512 + n] = hn;
      out[(size_t)32 * 2048 * 512 + (size_t)batch * 512 + n] = hn;
    }
  }
}

extern "C" void kernel_launch(void* const* d_in, const int* in_sizes, int n_in,
                              void* d_out, int out_size, void* d_ws, size_t ws_size,
                              hipStream_t stream) {
  (void)in_sizes; (void)n_in; (void)out_size;
  const float* x    = (const float*)d_in[0];
  const float* Wx   = (const float*)d_in[1];
  const float* Wh   = (const float*)d_in[2];
  const float* bias = (const float*)d_in[3];
  float* out = (float*)d_out;
  char* ws = (char*)d_ws;

  // gh_mode: rhbuf[64KB] | hbuf[64KB] ... gh at 2621440
  // fallback: Pbuf[2MB] | zbuf[512KB] (overlaps rhbuf/hbuf region; gh unused)
  uint32_t* rhbuf = (uint32_t*)ws;
  uint32_t* hbuf  = (uint32_t*)(ws + 65536);
  uint64_t* Pbuf  = (uint64_t*)ws;
  uint64_t* zbuf  = (uint64_t*)(ws + 2097152);
  _Float16* gh    = (_Float16*)(ws + 2621440);

  hipMemsetAsync(ws, 0, 2621440, stream);  // reset exchange tags (replay-safe)
  const bool gh_mode = ws_size >= (size_t)2621440 + 67108864ull;
  if (gh_mode) {
    gemm_gx<<<512 * 12, 256, 0, stream>>>(x, Wx, bias, (_Float16*)d_out, gh, 12);
    gru_scan_mfma<<<32, 512, 0, stream>>>((const _Float16*)d_out, gh, Wh, out,
                                          rhbuf, hbuf);
  } else {
    gemm_gx<<<512 * 8, 256, 0, stream>>>(x, Wx, bias, (_Float16*)d_out, gh, 8);
    gru_scan_fb<false><<<256, 512, 0, stream>>>(x, Wx, Wh, bias,
                                                (const _Float16*)d_out, gh, out,
                                                Pbuf, zbuf);
  }
}

// Round 13
// 23246.342 us; speedup vs baseline: 1.2180x; 1.2180x over previous
//
#include <hip/hip_runtime.h>
#include <stdint.h>
#include <stddef.h>

// GRU (B=32, T=2048, I=H=512, fp32 in/out).
// Phase 1 (MFMA GEMM): gz|gr -> fp16 INTO d_out (row-aliased); gh -> d_ws.
// Phase 2 (R13): persistent scan, 256 WGs = 16 groups x 16 slices.
//   Group = 2 batches (p, p+16) double-pumped; slice = 32 hidden cols.
//   z/r weights: LDS K-chunk-major [g][kc][col][8] -> conflict-free b128.
//   Candidate K-slice = own cols' rh (no rh exchange). Exchange: P fp16+tag16
//   u32 (16 slices contiguous per col), z tagged-u64 f32, agent scope only
//   (R9/R10: consumer-cacheable polls livelock). A/B phase alternation hides
//   the exchange RTT; combine loads pre-issued one phase early.
// Fallback (!gh_mode): R8 scalar scan.

#define AGENT __HIP_MEMORY_SCOPE_AGENT

typedef _Float16 h2v __attribute__((ext_vector_type(2)));
typedef _Float16 half8 __attribute__((ext_vector_type(8)));
typedef float f32x4 __attribute__((ext_vector_type(4)));

__device__ __forceinline__ uint32_t pk2u(float a, float b) {
  h2v r; r[0] = (_Float16)a; r[1] = (_Float16)b;
  return __builtin_bit_cast(uint32_t, r);
}
__device__ __forceinline__ h2v bc2(uint32_t u) { return __builtin_bit_cast(h2v, u); }
__device__ __forceinline__ float dot2f(h2v a, h2v b, float c) {
#if __has_builtin(__builtin_amdgcn_fdot2)
  return __builtin_amdgcn_fdot2(a, b, c, false);
#else
  return fmaf((float)a[1], (float)b[1], fmaf((float)a[0], (float)b[0], c));
#endif
}
__device__ __forceinline__ float sigmoidf_(float x) { return 1.0f / (1.0f + __expf(-x)); }
__device__ __forceinline__ float tanhf_(float x) { return 1.0f - 2.0f / (1.0f + __expf(2.0f * x)); }

__device__ __forceinline__ uint32_t ald32(const uint32_t* p) {
  return __hip_atomic_load(p, __ATOMIC_RELAXED, AGENT);
}
__device__ __forceinline__ void ast32(uint32_t* p, uint32_t v) {
  __hip_atomic_store(p, v, __ATOMIC_RELAXED, AGENT);
}
__device__ __forceinline__ uint64_t ald64(const uint64_t* p) {
  return __hip_atomic_load(p, __ATOMIC_RELAXED, AGENT);
}
__device__ __forceinline__ void ast64(uint64_t* p, uint64_t v) {
  __hip_atomic_store(p, v, __ATOMIC_RELAXED, AGENT);
}
__device__ __forceinline__ float f16b2f(uint32_t w) {
  return (float)__builtin_bit_cast(_Float16, (unsigned short)(w & 0xffffu));
}

// ---------------- Phase 1: gate GEMM  [65536 x 512] @ [512 x N*128] -> fp16 ----------------
__global__ __launch_bounds__(256) void gemm_gx(const float* __restrict__ x,
                                               const float* __restrict__ Wx,
                                               const float* __restrict__ bias,
                                               _Float16* gzr,   // [65536][1024] (aliases out)
                                               _Float16* gh,    // [65536][512] in ws (opt)
                                               int nTN) {
  __shared__ alignas(16) _Float16 Alds[128 * 68];
  __shared__ alignas(16) _Float16 Blds[128 * 68];
  const int tid = threadIdx.x;
  const int bid = blockIdx.x;
  const int tm = bid / nTN, tn = bid % nTN;
  const int m0 = tm << 7, n0 = tn << 7;
  const int lane = tid & 63;
  const int wv = tid >> 6, wm = wv >> 1, wn = wv & 1;
  const int l15 = lane & 15, lhi = lane >> 4;
  f32x4 acc[4][4] = {};

  for (int k0 = 0; k0 < 512; k0 += 64) {
#pragma unroll
    for (int r = 0; r < 8; ++r) {
      int m = r * 16 + (tid >> 4);
      int k = (tid & 15) * 4;
      float4 v = *(const float4*)&x[(size_t)(m0 + m) * 512 + k0 + k];
      union { _Float16 h[4]; uint2 u; } cv;
      cv.h[0] = (_Float16)v.x; cv.h[1] = (_Float16)v.y;
      cv.h[2] = (_Float16)v.z; cv.h[3] = (_Float16)v.w;
      *(uint2*)&Alds[m * 68 + k] = cv.u;
    }
#pragma unroll
    for (int u = 0; u < 8; ++u) {
      int n = tid & 127;
      int k = (tid >> 7) * 32 + u * 4;
      int ng = n0 + n;
      const float* wp = Wx + ((size_t)(ng >> 9) << 18) + (size_t)(k0 + k) * 512 + (ng & 511);
      union { _Float16 h[4]; uint2 u2; } cv;
      cv.h[0] = (_Float16)wp[0];    cv.h[1] = (_Float16)wp[512];
      cv.h[2] = (_Float16)wp[1024]; cv.h[3] = (_Float16)wp[1536];
      *(uint2*)&Blds[n * 68 + k] = cv.u2;
    }
    __syncthreads();
#pragma unroll
    for (int kk = 0; kk < 2; ++kk) {
      int q = kk * 4 + lhi;
      half8 af[4], bf[4];
#pragma unroll
      for (int fm = 0; fm < 4; ++fm) {
        const _Float16* pa = &Alds[(wm * 64 + fm * 16 + l15) * 68 + q * 8];
        union { uint2 u[2]; half8 h; } cv;
        cv.u[0] = *(const uint2*)pa; cv.u[1] = *(const uint2*)(pa + 4);
        af[fm] = cv.h;
      }
#pragma unroll
      for (int fn = 0; fn < 4; ++fn) {
        const _Float16* pb = &Blds[(wn * 64 + fn * 16 + l15) * 68 + q * 8];
        union { uint2 u[2]; half8 h; } cv;
        cv.u[0] = *(const uint2*)pb; cv.u[1] = *(const uint2*)(pb + 4);
        bf[fn] = cv.h;
      }
#pragma unroll
      for (int fm = 0; fm < 4; ++fm)
#pragma unroll
        for (int fn = 0; fn < 4; ++fn)
          acc[fm][fn] = __builtin_amdgcn_mfma_f32_16x16x32_f16(af[fm], bf[fn], acc[fm][fn], 0, 0, 0);
    }
    __syncthreads();
  }
#pragma unroll
  for (int fn = 0; fn < 4; ++fn) {
    int col = n0 + wn * 64 + fn * 16 + l15;
    float bv = bias[col];
#pragma unroll
    for (int fm = 0; fm < 4; ++fm) {
#pragma unroll
      for (int q2 = 0; q2 < 4; ++q2) {
        int row = m0 + wm * 64 + fm * 16 + lhi * 4 + q2;
        _Float16 val = (_Float16)(acc[fm][fn][q2] + bv);
        if (n0 < 1024) gzr[(size_t)row * 1024 + col] = val;
        else           gh[(size_t)row * 512 + (col - 1024)] = val;
      }
    }
  }
}

// ---------------- Phase 2 (R13): S=16 x D=2 persistent scan ----------------
__device__ __forceinline__ bool tagsok(const uint32_t pv[16], uint64_t zv, uint32_t want) {
  bool ok = ((uint32_t)(zv >> 32) == want);
#pragma unroll
  for (int q = 0; q < 16; ++q) ok &= ((pv[q] >> 16) == want);
  return ok;
}

__global__ __launch_bounds__(512) void gru_scan2(
    const _Float16* gzr,            // [65536][1024] (aliases out!)
    const _Float16* ghg,            // [65536][512]
    const float* __restrict__ Wh,   // [3][512][512]
    float* out,                     // [32][2048][512] + [32][512]
    uint32_t* __restrict__ Pbuf,    // [2][32][512 col][16 slice] u32 {tag16|fp16}
    uint64_t* __restrict__ zbuf) {  // [2][32][512] u64 {tag32|f32}
  __shared__ alignas(16) _Float16 wzK[2 * 64 * 32 * 8];  // [g][kc][col][8] : 64KB
  __shared__ alignas(16) _Float16 hA[512], hB[512];
  __shared__ alignas(16) _Float16 rhA[32], rhB[32];
  __shared__ alignas(16) float zrp[2][16][32];

  const int T = threadIdx.x;
  const int bid = blockIdx.x;          // 0..255
  const int s = bid >> 4;              // slice 0..15 -> cols [s*32, s*32+32)
  const int p = bid & 15;              // group 0..15 (16 WGs of group p: bids ≡ p mod 16 -> same XCD)
  const int c0 = s * 32;
  const int bA = p, bB = p + 16;
  const int j = T & 31, sub = T >> 5;  // z/r: col-in-slice, K-16th

  // ---- z/r weight fill: wzK[g][kc][j][e] = W_g[kc*8+e][c0+j] ----
  for (int g = 0; g < 2; ++g) {
    const float* W = Wh + (size_t)g * 262144;
    for (int kc = sub; kc < 64; kc += 16) {
#pragma unroll
      for (int e = 0; e < 8; ++e) {
        int k = kc * 8 + e;
        wzK[((g * 64 + kc) * 32 + j) * 8 + e] = (_Float16)W[(size_t)k * 512 + c0 + j];
      }
    }
  }
  // ---- candidate weights: 16 u32/thread (K rows = own cols c0..c0+31) ----
  uint32_t wh2[16];
  {
    const float* Whh = Wh + 524288;
#pragma unroll
    for (int i = 0; i < 16; ++i) {
      int kk = c0 + 2 * i;
      wh2[i] = pk2u(Whh[(size_t)kk * 512 + T], Whh[(size_t)(kk + 1) * 512 + T]);
    }
  }
  hA[T] = (_Float16)0.0f;
  hB[T] = (_Float16)0.0f;
  float hregA = 0.f, hregB = 0.f;

  const size_t rbA = (size_t)bA * 2048, rbB = (size_t)bB * 2048;
  float gzA_p = 0.f, grA_p = 0.f, gzB_p = 0.f, grB_p = 0.f;
  float gzA_c = 0.f, grA_c = 0.f, gzB_c = 0.f, grB_c = 0.f;
  float ghA_p, ghB_p, ghA_c = 0.f, ghB_c = 0.f;
  if (T < 32) {
    gzA_p = (float)gzr[rbA * 1024 + c0 + T];
    gzB_p = (float)gzr[rbB * 1024 + c0 + T];
  } else if (T < 64) {
    grA_p = (float)gzr[rbA * 1024 + 512 + c0 + (T - 32)];
    grB_p = (float)gzr[rbB * 1024 + 512 + c0 + (T - 32)];
  }
  ghA_p = (float)ghg[rbA * 512 + T];
  ghB_p = (float)ghg[rbB * 512 + T];

  // exchange pointers (u32 / u64 elements)
  uint32_t* PmA = Pbuf + ((size_t)bA * 512 + T) * 16 + s;   // + par*262144
  uint32_t* PmB = Pbuf + ((size_t)bB * 512 + T) * 16 + s;
  const uint32_t* PrA = Pbuf + ((size_t)bA * 512 + T) * 16; // col T's 16 words
  const uint32_t* PrB = Pbuf + ((size_t)bB * 512 + T) * 16;
  uint64_t* zmA = zbuf + (size_t)bA * 512 + c0 + (T & 31);  // + par*16384 (T<32 only)
  uint64_t* zmB = zbuf + (size_t)bB * 512 + c0 + (T & 31);
  const uint64_t* zrdA = zbuf + (size_t)bA * 512 + T;
  const uint64_t* zrdB = zbuf + (size_t)bB * 512 + T;

  uint32_t pvA[16], pvB[16];
  uint64_t zvA = 0, zvB = 0;
#pragma unroll
  for (int q = 0; q < 16; ++q) { pvA[q] = 0; pvB[q] = 0; }

  for (int t = 0; t < 2048; ++t) {
    const size_t poC = ((t - 1) & 1) ? 262144 : 0;  // combine parity (step t-1)
    const size_t zoC = ((t - 1) & 1) ? 16384 : 0;
    const size_t poN = (t & 1) ? 262144 : 0;        // publish parity (step t)
    const size_t zoN = (t & 1) ? 16384 : 0;
    const uint32_t want = (uint32_t)t;              // tag of step t-1 data
    const uint32_t tagN = (uint32_t)(t + 1);

    // ================= A =================
    if (t > 0) {
      while (!tagsok(pvA, zvA, want)) {
        __builtin_amdgcn_s_sleep(1);
        zvA = ald64(zrdA + zoC);
#pragma unroll
        for (int q = 0; q < 16; ++q)
          if ((pvA[q] >> 16) != want) pvA[q] = ald32(PrA + poC + q);
      }
      float hsum = 0.f;
#pragma unroll
      for (int q = 0; q < 16; ++q) hsum += f16b2f(pvA[q]);
      float zf = __uint_as_float((uint32_t)zvA);
      float htil = tanhf_(ghA_c + hsum);
      float hn = fmaf(zf, htil - hregA, hregA);
      if (sub == s) out[(rbA + (t - 1)) * 512 + T] = hn;  // own 32-col stripe
      hregA = hn;
      hA[T] = (_Float16)hn;
    }
    gzA_c = gzA_p; grA_c = grA_p; ghA_c = ghA_p;
    __syncthreads();  // B1a: hA visible
    if (t < 2047) {
      size_t r1 = rbA + t + 1;
      if (T < 32)      gzA_p = (float)gzr[r1 * 1024 + c0 + T];
      else if (T < 64) grA_p = (float)gzr[r1 * 1024 + 512 + c0 + (T - 32)];
      ghA_p = (float)ghg[r1 * 512 + T];
    }
    {  // z/r GEMV A: thread (j,sub) covers K [sub*32, sub*32+32)
      float za = 0.f, ra = 0.f;
#pragma unroll
      for (int cc = 0; cc < 4; ++cc) {
        int kc = sub * 4 + cc;
        uint4 hu = *(const uint4*)&hA[kc * 8];                       // broadcast
        uint4 wz = *(const uint4*)&wzK[(kc * 32 + j) * 8];           // stride-16B
        uint4 wr = *(const uint4*)&wzK[((64 + kc) * 32 + j) * 8];
        za = dot2f(bc2(hu.x), bc2(wz.x), za); za = dot2f(bc2(hu.y), bc2(wz.y), za);
        za = dot2f(bc2(hu.z), bc2(wz.z), za); za = dot2f(bc2(hu.w), bc2(wz.w), za);
        ra = dot2f(bc2(hu.x), bc2(wr.x), ra); ra = dot2f(bc2(hu.y), bc2(wr.y), ra);
        ra = dot2f(bc2(hu.z), bc2(wr.z), ra); ra = dot2f(bc2(hu.w), bc2(wr.w), ra);
      }
      zrp[0][sub][j] = za;
      zrp[1][sub][j] = ra;
    }
    if (t > 0) {  // pre-issue B-combine (PB(t-1) published end of last iter)
      zvB = ald64(zrdB + zoC);
#pragma unroll
      for (int q = 0; q < 16; ++q) pvB[q] = ald32(PrB + poC + q);
    }
    __syncthreads();  // B2a: zrp ready
    if (T < 64) {
      const int g = T >> 5, jj = T & 31;
      float sum = 0.f;
#pragma unroll
      for (int q = 0; q < 16; ++q) sum += zrp[g][q][jj];
      if (g == 0) {
        float z = sigmoidf_(sum + gzA_c);
        ast64(zmA + zoN, ((uint64_t)tagN << 32) | (uint32_t)__float_as_uint(z));
      } else {
        float r = sigmoidf_(sum + grA_c);
        rhA[jj] = (_Float16)(r * (float)hA[c0 + jj]);
      }
    }
    __syncthreads();  // B3a: rhA ready
    {  // candidate A: P[T] += rh(own cols) @ Whh -> publish
      float pa = 0.f;
#pragma unroll
      for (int i = 0; i < 8; ++i) {
        uint2 ru = *(const uint2*)&rhA[4 * i];  // broadcast
        pa = dot2f(bc2(ru.x), bc2(wh2[2 * i]), pa);
        pa = dot2f(bc2(ru.y), bc2(wh2[2 * i + 1]), pa);
      }
      unsigned short pb = __builtin_bit_cast(unsigned short, (_Float16)pa);
      ast32(PmA + poN, (tagN << 16) | (uint32_t)pb);
    }

    // ================= B =================
    if (t > 0) {
      while (!tagsok(pvB, zvB, want)) {
        __builtin_amdgcn_s_sleep(1);
        zvB = ald64(zrdB + zoC);
#pragma unroll
        for (int q = 0; q < 16; ++q)
          if ((pvB[q] >> 16) != want) pvB[q] = ald32(PrB + poC + q);
      }
      float hsum = 0.f;
#pragma unroll
      for (int q = 0; q < 16; ++q) hsum += f16b2f(pvB[q]);
      float zf = __uint_as_float((uint32_t)zvB);
      float htil = tanhf_(ghB_c + hsum);
      float hn = fmaf(zf, htil - hregB, hregB);
      if (sub == s) out[(rbB + (t - 1)) * 512 + T] = hn;
      hregB = hn;
      hB[T] = (_Float16)hn;
    }
    gzB_c = gzB_p; grB_c = grB_p; ghB_c = ghB_p;
    __syncthreads();  // B1b
    if (t < 2047) {
      size_t r1 = rbB + t + 1;
      if (T < 32)      gzB_p = (float)gzr[r1 * 1024 + c0 + T];
      else if (T < 64) grB_p = (float)gzr[r1 * 1024 + 512 + c0 + (T - 32)];
      ghB_p = (float)ghg[r1 * 512 + T];
    }
    {  // z/r GEMV B
      float za = 0.f, ra = 0.f;
#pragma unroll
      for (int cc = 0; cc < 4; ++cc) {
        int kc = sub * 4 + cc;
        uint4 hu = *(const uint4*)&hB[kc * 8];
        uint4 wz = *(const uint4*)&wzK[(kc * 32 + j) * 8];
        uint4 wr = *(const uint4*)&wzK[((64 + kc) * 32 + j) * 8];
        za = dot2f(bc2(hu.x), bc2(wz.x), za); za = dot2f(bc2(hu.y), bc2(wz.y), za);
        za = dot2f(bc2(hu.z), bc2(wz.z), za); za = dot2f(bc2(hu.w), bc2(wz.w), za);
        ra = dot2f(bc2(hu.x), bc2(wr.x), ra); ra = dot2f(bc2(hu.y), bc2(wr.y), ra);
        ra = dot2f(bc2(hu.z), bc2(wr.z), ra); ra = dot2f(bc2(hu.w), bc2(wr.w), ra);
      }
      zrp[0][sub][j] = za;
      zrp[1][sub][j] = ra;
    }
    {  // pre-issue A-combine for next iter (PA(t) published just above in A-cand)
      zvA = ald64(zrdA + zoN);
#pragma unroll
      for (int q = 0; q < 16; ++q) pvA[q] = ald32(PrA + poN + q);
    }
    __syncthreads();  // B2b
    if (T < 64) {
      const int g = T >> 5, jj = T & 31;
      float sum = 0.f;
#pragma unroll
      for (int q = 0; q < 16; ++q) sum += zrp[g][q][jj];
      if (g == 0) {
        float z = sigmoidf_(sum + gzB_c);
        ast64(zmB + zoN, ((uint64_t)tagN << 32) | (uint32_t)__float_as_uint(z));
      } else {
        float r = sigmoidf_(sum + grB_c);
        rhB[jj] = (_Float16)(r * (float)hB[c0 + jj]);
      }
    }
    __syncthreads();  // B3b
    {  // candidate B -> publish
      float pa = 0.f;
#pragma unroll
      for (int i = 0; i < 8; ++i) {
        uint2 ru = *(const uint2*)&rhB[4 * i];
        pa = dot2f(bc2(ru.x), bc2(wh2[2 * i]), pa);
        pa = dot2f(bc2(ru.y), bc2(wh2[2 * i + 1]), pa);
      }
      unsigned short pb = __builtin_bit_cast(unsigned short, (_Float16)pa);
      ast32(PmB + poN, (tagN << 16) | (uint32_t)pb);
    }
  }

  // ---- epilogue: combine step 2047 (parity 1, tag 2048) ----
  {
    const uint32_t want = 2048u;
    while (!tagsok(pvA, zvA, want)) {  // pvA pre-issued in final B-section
      __builtin_amdgcn_s_sleep(1);
      zvA = ald64(zrdA + 16384);
#pragma unroll
      for (int q = 0; q < 16; ++q)
        if ((pvA[q] >> 16) != want) pvA[q] = ald32(PrA + 262144 + q);
    }
    float hsum = 0.f;
#pragma unroll
    for (int q = 0; q < 16; ++q) hsum += f16b2f(pvA[q]);
    float zf = __uint_as_float((uint32_t)zvA);
    float htil = tanhf_(ghA_c + hsum);
    float hn = fmaf(zf, htil - hregA, hregA);
    if (sub == s) {
      out[(rbA + 2047) * 512 + T] = hn;
      out[(size_t)32 * 2048 * 512 + (size_t)bA * 512 + T] = hn;
    }
  }
  {
    const uint32_t want = 2048u;
    zvB = ald64(zrdB + 16384);
#pragma unroll
    for (int q = 0; q < 16; ++q) pvB[q] = ald32(PrB + 262144 + q);
    while (!tagsok(pvB, zvB, want)) {
      __builtin_amdgcn_s_sleep(1);
      zvB = ald64(zrdB + 16384);
#pragma unroll
      for (int q = 0; q < 16; ++q)
        if ((pvB[q] >> 16) != want) pvB[q] = ald32(PrB + 262144 + q);
    }
    float hsum = 0.f;
#pragma unroll
    for (int q = 0; q < 16; ++q) hsum += f16b2f(pvB[q]);
    float zf = __uint_as_float((uint32_t)zvB);
    float htil = tanhf_(ghB_c + hsum);
    float hn = fmaf(zf, htil - hregB, hregB);
    if (sub == s) {
      out[(rbB + 2047) * 512 + T] = hn;
      out[(size_t)32 * 2048 * 512 + (size_t)bB * 512 + T] = hn;
    }
  }
}

// ---------------- Fallback scan (R8 scalar, !gh_mode) ----------------
__global__ __launch_bounds__(512) void gru_scan_fb(
    const float* __restrict__ x, const float* __restrict__ Wx,
    const float* __restrict__ Wh, const float* __restrict__ bias,
    const _Float16* gzr, float* out,
    uint64_t* __restrict__ Pbuf, uint64_t* __restrict__ zbuf) {
  __shared__ alignas(16) float zrp[2][8][64];
  __shared__ alignas(16) _Float16 wzrL[2 * 64 * 516];
  __shared__ alignas(16) _Float16 h16[512];
  __shared__ alignas(16) _Float16 rh16[64];
  __shared__ alignas(16) _Float16 x16s[64];

  const int T = threadIdx.x;
  const int bid = blockIdx.x;
  const int xcd = bid & 7, ii = bid >> 3;
  const int batch = xcd * 4 + (ii >> 3);
  const int slice = ii & 7;
  const int wv = T >> 6, ln = T & 63, n = T;
  {
    const int cc = T & 63, kb = T >> 6;
#pragma unroll 4
    for (int g = 0; g < 2; ++g) {
      const float* W = Wh + (size_t)g * 262144 + slice * 64 + cc;
      for (int i = 0; i < 64; ++i) {
        int k = kb + 8 * i;
        wzrL[(g * 64 + cc) * 516 + k] = (_Float16)W[(size_t)k * 512];
      }
    }
  }
  uint32_t wh2[32], wx2[32];
  {
    const float* Whh = Wh + 524288;
    const float* Wxh = Wx + 524288;
#pragma unroll
    for (int jj = 0; jj < 32; ++jj) {
      int kk = slice * 64 + 2 * jj;
      wh2[jj] = pk2u(Whh[(size_t)kk * 512 + n], Whh[(size_t)(kk + 1) * 512 + n]);
      wx2[jj] = pk2u(Wxh[(size_t)kk * 512 + n], Wxh[(size_t)(kk + 1) * 512 + n]);
    }
  }
  const float bh = bias[1024 + n];
  float hreg = 0.0f;
  h16[T] = (_Float16)0.0f;
  const size_t rowbase = (size_t)batch * 2048;
  float gz_p = 0.f, gr_p = 0.f, gz_cur = 0.f, gr_cur = 0.f, x_p = 0.f;
  if (T < 64)       gz_p = (float)gzr[rowbase * 1024 + slice * 64 + T];
  else if (T < 128) gr_p = (float)gzr[rowbase * 1024 + 512 + slice * 64 + (T - 64)];
  if (T < 64) x_p = x[rowbase * 512 + slice * 64 + T];

  uint64_t* Pmine = Pbuf + ((size_t)batch * 8 + slice) * 512 + n;
  const uint64_t* Pread = Pbuf + ((size_t)batch * 8) * 512 + n;
  uint64_t* zmine = zbuf + (size_t)batch * 512 + slice * 64 + ln;
  const uint64_t* zread = zbuf + (size_t)batch * 512 + n;

  for (int t = 0; t < 2048; ++t) {
    if (t > 0) {
      const size_t po = ((t - 1) & 1) ? 131072 : 0;
      const size_t zo = ((t - 1) & 1) ? 16384 : 0;
      const uint32_t want = (uint32_t)t;
      uint64_t v[8];
#pragma unroll
      for (int g = 0; g < 8; ++g) v[g] = ald64(Pread + po + (size_t)g * 512);
      uint64_t zv = ald64(zread + zo);
      for (;;) {
        bool ok = true;
        if ((uint32_t)(zv >> 32) != want) { zv = ald64(zread + zo); ok = false; }
#pragma unroll
        for (int g = 0; g < 8; ++g)
          if ((uint32_t)(v[g] >> 32) != want) { v[g] = ald64(Pread + po + (size_t)g * 512); ok = false; }
        if (ok) break;
        __builtin_amdgcn_s_sleep(1);
      }
      float hsum = 0.f;
#pragma unroll
      for (int g = 0; g < 8; ++g) hsum += __uint_as_float((uint32_t)v[g]);
      float zf = __uint_as_float((uint32_t)zv);
      float htil = tanhf_(bh + hsum);
      float hn = fmaf(zf, htil - hreg, hreg);
      if (slice == 0) out[(rowbase + (t - 1)) * 512 + n] = hn;
      hreg = hn;
      h16[T] = (_Float16)hn;
    }
    gz_cur = gz_p; gr_cur = gr_p;
    if (T < 64) x16s[T] = (_Float16)x_p;
    __syncthreads();
    if (t < 2047) {
      size_t r1 = rowbase + t + 1;
      if (T < 64)       gz_p = (float)gzr[r1 * 1024 + slice * 64 + T];
      else if (T < 128) gr_p = (float)gzr[r1 * 1024 + 512 + slice * 64 + (T - 64)];
      if (T < 64) x_p = x[r1 * 512 + slice * 64 + T];
    }
    float za = 0.f, ra = 0.f;
    {
      const _Float16* wzp = &wzrL[ln * 516 + 64 * wv];
      const _Float16* wrp = &wzrL[(64 + ln) * 516 + 64 * wv];
      const _Float16* hp = &h16[64 * wv];
#pragma unroll
      for (int jj = 0; jj < 16; ++jj) {
        uint2 wzu = *(const uint2*)(wzp + 4 * jj);
        uint2 wru = *(const uint2*)(wrp + 4 * jj);
        uint2 hu = *(const uint2*)(hp + 4 * jj);
        za = dot2f(bc2(hu.x), bc2(wzu.x), za);
        za = dot2f(bc2(hu.y), bc2(wzu.y), za);
        ra = dot2f(bc2(hu.x), bc2(wru.x), ra);
        ra = dot2f(bc2(hu.y), bc2(wru.y), ra);
      }
    }
    zrp[0][wv][ln] = za;
    zrp[1][wv][ln] = ra;
    __syncthreads();
    const size_t po = (t & 1) ? 131072 : 0;
    const size_t zo = (t & 1) ? 16384 : 0;
    const uint64_t tagw = ((uint64_t)(uint32_t)(t + 1)) << 32;
    if (T < 128) {
      const int g = T >> 6, cc = T & 63;
      float sum = 0.f;
#pragma unroll
      for (int s2 = 0; s2 < 8; ++s2) sum += zrp[g][s2][cc];
      if (g == 0) {
        float z = sigmoidf_(sum + gz_cur);
        ast64(zmine + zo, tagw | (uint32_t)__float_as_uint(z));
      } else {
        float r = sigmoidf_(sum + gr_cur);
        rh16[cc] = (_Float16)(r * (float)h16[slice * 64 + cc]);
      }
    }
    __syncthreads();
    float pa = 0.f;
#pragma unroll
    for (int jj = 0; jj < 16; ++jj) {
      uint2 ru = *(const uint2*)&rh16[4 * jj];
      pa = dot2f(bc2(ru.x), bc2(wh2[2 * jj]), pa);
      pa = dot2f(bc2(ru.y), bc2(wh2[2 * jj + 1]), pa);
    }
#pragma unroll
    for (int jj = 0; jj < 16; ++jj) {
      uint2 xu = *(const uint2*)&x16s[4 * jj];
      pa = dot2f(bc2(xu.x), bc2(wx2[2 * jj]), pa);
      pa = dot2f(bc2(xu.y), bc2(wx2[2 * jj + 1]), pa);
    }
    ast64(Pmine + po, tagw | (uint32_t)__float_as_uint(pa));
    __syncthreads();
  }
  {
    const uint32_t want = 2048u;
    uint64_t v[8];
#pragma unroll
    for (int g = 0; g < 8; ++g) v[g] = ald64(Pread + 131072 + (size_t)g * 512);
    uint64_t zv = ald64(zread + 16384);
    for (;;) {
      bool ok = true;
      if ((uint32_t)(zv >> 32) != want) { zv = ald64(zread + 16384); ok = false; }
#pragma unroll
      for (int g = 0; g < 8; ++g)
        if ((uint32_t)(v[g] >> 32) != want) { v[g] = ald64(Pread + 131072 + (size_t)g * 512); ok = false; }
      if (ok) break;
      __builtin_amdgcn_s_sleep(1);
    }
    float hsum = 0.f;
#pragma unroll
    for (int g = 0; g < 8; ++g) hsum += __uint_as_float((uint32_t)v[g]);
    float zf = __uint_as_float((uint32_t)zv);
    float htil = tanhf_(bh + hsum);
    float hn = fmaf(zf, htil - hreg, hreg);
    if (slice == 0) {
      out[(rowbase + 2047) * 512 + n] = hn;
      out[(size_t)32 * 2048 * 512 + (size_t)batch * 512 + n] = hn;
    }
  }
}

extern "C" void kernel_launch(void* const* d_in, const int* in_sizes, int n_in,
                              void* d_out, int out_size, void* d_ws, size_t ws_size,
                              hipStream_t stream) {
  (void)in_sizes; (void)n_in; (void)out_size;
  const float* x    = (const float*)d_in[0];
  const float* Wx   = (const float*)d_in[1];
  const float* Wh   = (const float*)d_in[2];
  const float* bias = (const float*)d_in[3];
  float* out = (float*)d_out;
  char* ws = (char*)d_ws;

  // gh_mode layout: Pbuf u32 [2][32][512][16] = 2 MB | zbuf u64 [2][32][512] = 256 KB | gh @ 2621440
  // fallback layout: Pbuf u64 2 MB | zbuf u64 @ 2097152
  uint32_t* Pbuf2 = (uint32_t*)ws;
  uint64_t* zbuf2 = (uint64_t*)(ws + 2097152);
  uint64_t* PbufF = (uint64_t*)ws;
  uint64_t* zbufF = (uint64_t*)(ws + 2097152);
  _Float16* gh    = (_Float16*)(ws + 2621440);

  hipMemsetAsync(ws, 0, 2621440, stream);  // reset exchange tags (replay-safe)
  const bool gh_mode = ws_size >= (size_t)2621440 + 67108864ull;
  if (gh_mode) {
    gemm_gx<<<512 * 12, 256, 0, stream>>>(x, Wx, bias, (_Float16*)d_out, gh, 12);
    gru_scan2<<<256, 512, 0, stream>>>((const _Float16*)d_out, gh, Wh, out,
                                       Pbuf2, zbuf2);
  } else {
    gemm_gx<<<512 * 8, 256, 0, stream>>>(x, Wx, bias, (_Float16*)d_out, gh, 8);
    gru_scan_fb<<<256, 512, 0, stream>>>(x, Wx, Wh, bias, (const _Float16*)d_out,
                                         out, PbufF, zbufF);
  }
}

// Round 14
// 9034.587 us; speedup vs baseline: 3.1339x; 2.5730x over previous
//
#include <hip/hip_runtime.h>
#include <stdint.h>
#include <stddef.h>

// GRU (B=32, T=2048, I=H=512, fp32 in/out).
// Phase 1 (MFMA GEMM): gz|gr -> fp16 INTO d_out (row-aliased); gh -> d_ws.
// Phase 2 (R14): persistent scan, 256 WGs = 16 slices x 16 pairs.
//   Pair p = batches (p, p+16) double-pumped; slice = 32 hidden cols.
//   bid = slice*16 + p -> all 16 slices of a pair share one XCD (bid&7=p&7).
//   z/r weights: LDS K-chunk-major [g][kc][col][8] -> conflict-free b128.
//   Candidate K-slice = own cols' rh (no rh exchange).
//   R14 fix vs R13: P exchange layout is SLICE-MAJOR [par][b][slice][col]
//   u32 {tag16|fp16} -> each WG publishes 512 CONSECUTIVE u32 (agent stores
//   write through to HBM at line granularity; R13's [col][slice] scatter
//   caused 17 GB of write-amplified traffic = the regression).
// Fallback (!gh_mode): R8 scalar scan.

#define AGENT __HIP_MEMORY_SCOPE_AGENT

typedef _Float16 h2v __attribute__((ext_vector_type(2)));
typedef _Float16 half8 __attribute__((ext_vector_type(8)));
typedef float f32x4 __attribute__((ext_vector_type(4)));

__device__ __forceinline__ uint32_t pk2u(float a, float b) {
  h2v r; r[0] = (_Float16)a; r[1] = (_Float16)b;
  return __builtin_bit_cast(uint32_t, r);
}
__device__ __forceinline__ h2v bc2(uint32_t u) { return __builtin_bit_cast(h2v, u); }
__device__ __forceinline__ float dot2f(h2v a, h2v b, float c) {
#if __has_builtin(__builtin_amdgcn_fdot2)
  return __builtin_amdgcn_fdot2(a, b, c, false);
#else
  return fmaf((float)a[1], (float)b[1], fmaf((float)a[0], (float)b[0], c));
#endif
}
__device__ __forceinline__ float sigmoidf_(float x) { return 1.0f / (1.0f + __expf(-x)); }
__device__ __forceinline__ float tanhf_(float x) { return 1.0f - 2.0f / (1.0f + __expf(2.0f * x)); }

__device__ __forceinline__ uint32_t ald32(const uint32_t* p) {
  return __hip_atomic_load(p, __ATOMIC_RELAXED, AGENT);
}
__device__ __forceinline__ void ast32(uint32_t* p, uint32_t v) {
  __hip_atomic_store(p, v, __ATOMIC_RELAXED, AGENT);
}
__device__ __forceinline__ uint64_t ald64(const uint64_t* p) {
  return __hip_atomic_load(p, __ATOMIC_RELAXED, AGENT);
}
__device__ __forceinline__ void ast64(uint64_t* p, uint64_t v) {
  __hip_atomic_store(p, v, __ATOMIC_RELAXED, AGENT);
}
__device__ __forceinline__ float f16b2f(uint32_t w) {
  return (float)__builtin_bit_cast(_Float16, (unsigned short)(w & 0xffffu));
}

// ---------------- Phase 1: gate GEMM  [65536 x 512] @ [512 x N*128] -> fp16 ----------------
__global__ __launch_bounds__(256) void gemm_gx(const float* __restrict__ x,
                                               const float* __restrict__ Wx,
                                               const float* __restrict__ bias,
                                               _Float16* gzr,   // [65536][1024] (aliases out)
                                               _Float16* gh,    // [65536][512] in ws (opt)
                                               int nTN) {
  __shared__ alignas(16) _Float16 Alds[128 * 68];
  __shared__ alignas(16) _Float16 Blds[128 * 68];
  const int tid = threadIdx.x;
  const int bid = blockIdx.x;
  const int tm = bid / nTN, tn = bid % nTN;
  const int m0 = tm << 7, n0 = tn << 7;
  const int lane = tid & 63;
  const int wv = tid >> 6, wm = wv >> 1, wn = wv & 1;
  const int l15 = lane & 15, lhi = lane >> 4;
  f32x4 acc[4][4] = {};

  for (int k0 = 0; k0 < 512; k0 += 64) {
#pragma unroll
    for (int r = 0; r < 8; ++r) {
      int m = r * 16 + (tid >> 4);
      int k = (tid & 15) * 4;
      float4 v = *(const float4*)&x[(size_t)(m0 + m) * 512 + k0 + k];
      union { _Float16 h[4]; uint2 u; } cv;
      cv.h[0] = (_Float16)v.x; cv.h[1] = (_Float16)v.y;
      cv.h[2] = (_Float16)v.z; cv.h[3] = (_Float16)v.w;
      *(uint2*)&Alds[m * 68 + k] = cv.u;
    }
#pragma unroll
    for (int u = 0; u < 8; ++u) {
      int n = tid & 127;
      int k = (tid >> 7) * 32 + u * 4;
      int ng = n0 + n;
      const float* wp = Wx + ((size_t)(ng >> 9) << 18) + (size_t)(k0 + k) * 512 + (ng & 511);
      union { _Float16 h[4]; uint2 u2; } cv;
      cv.h[0] = (_Float16)wp[0];    cv.h[1] = (_Float16)wp[512];
      cv.h[2] = (_Float16)wp[1024]; cv.h[3] = (_Float16)wp[1536];
      *(uint2*)&Blds[n * 68 + k] = cv.u2;
    }
    __syncthreads();
#pragma unroll
    for (int kk = 0; kk < 2; ++kk) {
      int q = kk * 4 + lhi;
      half8 af[4], bf[4];
#pragma unroll
      for (int fm = 0; fm < 4; ++fm) {
        const _Float16* pa = &Alds[(wm * 64 + fm * 16 + l15) * 68 + q * 8];
        union { uint2 u[2]; half8 h; } cv;
        cv.u[0] = *(const uint2*)pa; cv.u[1] = *(const uint2*)(pa + 4);
        af[fm] = cv.h;
      }
#pragma unroll
      for (int fn = 0; fn < 4; ++fn) {
        const _Float16* pb = &Blds[(wn * 64 + fn * 16 + l15) * 68 + q * 8];
        union { uint2 u[2]; half8 h; } cv;
        cv.u[0] = *(const uint2*)pb; cv.u[1] = *(const uint2*)(pb + 4);
        bf[fn] = cv.h;
      }
#pragma unroll
      for (int fm = 0; fm < 4; ++fm)
#pragma unroll
        for (int fn = 0; fn < 4; ++fn)
          acc[fm][fn] = __builtin_amdgcn_mfma_f32_16x16x32_f16(af[fm], bf[fn], acc[fm][fn], 0, 0, 0);
    }
    __syncthreads();
  }
#pragma unroll
  for (int fn = 0; fn < 4; ++fn) {
    int col = n0 + wn * 64 + fn * 16 + l15;
    float bv = bias[col];
#pragma unroll
    for (int fm = 0; fm < 4; ++fm) {
#pragma unroll
      for (int q2 = 0; q2 < 4; ++q2) {
        int row = m0 + wm * 64 + fm * 16 + lhi * 4 + q2;
        _Float16 val = (_Float16)(acc[fm][fn][q2] + bv);
        if (n0 < 1024) gzr[(size_t)row * 1024 + col] = val;
        else           gh[(size_t)row * 512 + (col - 1024)] = val;
      }
    }
  }
}

// ---------------- Phase 2 (R14): S=16 x D=2 persistent scan ----------------
__device__ __forceinline__ bool tagsok(const uint32_t pv[16], uint64_t zv, uint32_t want) {
  bool ok = ((uint32_t)(zv >> 32) == want);
#pragma unroll
  for (int q = 0; q < 16; ++q) ok &= ((pv[q] >> 16) == want);
  return ok;
}

__global__ __launch_bounds__(512) void gru_scan2(
    const _Float16* gzr,            // [65536][1024] (aliases out!)
    const _Float16* ghg,            // [65536][512]
    const float* __restrict__ Wh,   // [3][512][512]
    float* out,                     // [32][2048][512] + [32][512]
    uint32_t* __restrict__ Pbuf,    // [2][32][16 slice][512 col] u32 {tag16|fp16}
    uint64_t* __restrict__ zbuf) {  // [2][32][512] u64 {tag32|f32}
  __shared__ alignas(16) _Float16 wzK[2 * 64 * 32 * 8];  // [g][kc][col][8] : 64KB
  __shared__ alignas(16) _Float16 hA[512], hB[512];
  __shared__ alignas(16) _Float16 rhA[32], rhB[32];
  __shared__ alignas(16) float zrp[2][16][32];

  const int T = threadIdx.x;
  const int bid = blockIdx.x;          // 0..255
  const int s = bid >> 4;              // slice 0..15 -> cols [s*32, s*32+32)
  const int p = bid & 15;              // pair 0..15 (16 WGs of pair p: bids ≡ p mod 16 -> same XCD)
  const int c0 = s * 32;
  const int bA = p, bB = p + 16;
  const int j = T & 31, sub = T >> 5;  // z/r: col-in-slice, K-16th

  // ---- z/r weight fill: wzK[g][kc][j][e] = W_g[kc*8+e][c0+j] ----
  for (int g = 0; g < 2; ++g) {
    const float* W = Wh + (size_t)g * 262144;
    for (int kc = sub; kc < 64; kc += 16) {
#pragma unroll
      for (int e = 0; e < 8; ++e) {
        int k = kc * 8 + e;
        wzK[((g * 64 + kc) * 32 + j) * 8 + e] = (_Float16)W[(size_t)k * 512 + c0 + j];
      }
    }
  }
  // ---- candidate weights: 16 u32/thread (K rows = own cols c0..c0+31) ----
  uint32_t wh2[16];
  {
    const float* Whh = Wh + 524288;
#pragma unroll
    for (int i = 0; i < 16; ++i) {
      int kk = c0 + 2 * i;
      wh2[i] = pk2u(Whh[(size_t)kk * 512 + T], Whh[(size_t)(kk + 1) * 512 + T]);
    }
  }
  hA[T] = (_Float16)0.0f;
  hB[T] = (_Float16)0.0f;
  float hregA = 0.f, hregB = 0.f;

  const size_t rbA = (size_t)bA * 2048, rbB = (size_t)bB * 2048;
  float gzA_p = 0.f, grA_p = 0.f, gzB_p = 0.f, grB_p = 0.f;
  float gzA_c = 0.f, grA_c = 0.f, gzB_c = 0.f, grB_c = 0.f;
  float ghA_p, ghB_p, ghA_c = 0.f, ghB_c = 0.f;
  if (T < 32) {
    gzA_p = (float)gzr[rbA * 1024 + c0 + T];
    gzB_p = (float)gzr[rbB * 1024 + c0 + T];
  } else if (T < 64) {
    grA_p = (float)gzr[rbA * 1024 + 512 + c0 + (T - 32)];
    grB_p = (float)gzr[rbB * 1024 + 512 + c0 + (T - 32)];
  }
  ghA_p = (float)ghg[rbA * 512 + T];
  ghB_p = (float)ghg[rbB * 512 + T];

  // exchange pointers — SLICE-MAJOR coalesced: P[par][b][slice][col]
  uint32_t* PmA = Pbuf + ((size_t)bA * 16 + s) * 512 + T;   // + par*262144
  uint32_t* PmB = Pbuf + ((size_t)bB * 16 + s) * 512 + T;
  const uint32_t* PrA = Pbuf + (size_t)bA * 8192 + T;       // slice q at +q*512
  const uint32_t* PrB = Pbuf + (size_t)bB * 8192 + T;
  uint64_t* zmA = zbuf + (size_t)bA * 512 + c0 + (T & 31);  // + par*16384 (T<32 publish)
  uint64_t* zmB = zbuf + (size_t)bB * 512 + c0 + (T & 31);
  const uint64_t* zrdA = zbuf + (size_t)bA * 512 + T;
  const uint64_t* zrdB = zbuf + (size_t)bB * 512 + T;

  uint32_t pvA[16], pvB[16];
  uint64_t zvA = 0, zvB = 0;
#pragma unroll
  for (int q = 0; q < 16; ++q) { pvA[q] = 0; pvB[q] = 0; }

  for (int t = 0; t < 2048; ++t) {
    const size_t poC = ((t - 1) & 1) ? 262144 : 0;  // combine parity (step t-1)
    const size_t zoC = ((t - 1) & 1) ? 16384 : 0;
    const size_t poN = (t & 1) ? 262144 : 0;        // publish parity (step t)
    const size_t zoN = (t & 1) ? 16384 : 0;
    const uint32_t want = (uint32_t)t;              // tag of step t-1 data
    const uint32_t tagN = (uint32_t)(t + 1);

    // ================= A =================
    if (t > 0) {
      while (!tagsok(pvA, zvA, want)) {
        __builtin_amdgcn_s_sleep(1);
        zvA = ald64(zrdA + zoC);
#pragma unroll
        for (int q = 0; q < 16; ++q)
          if ((pvA[q] >> 16) != want) pvA[q] = ald32(PrA + poC + (size_t)q * 512);
      }
      float hsum = 0.f;
#pragma unroll
      for (int q = 0; q < 16; ++q) hsum += f16b2f(pvA[q]);
      float zf = __uint_as_float((uint32_t)zvA);
      float htil = tanhf_(ghA_c + hsum);
      float hn = fmaf(zf, htil - hregA, hregA);
      if (sub == s) out[(rbA + (t - 1)) * 512 + T] = hn;  // own 32-col stripe
      hregA = hn;
      hA[T] = (_Float16)hn;
    }
    gzA_c = gzA_p; grA_c = grA_p; ghA_c = ghA_p;
    __syncthreads();  // B1a: hA visible
    if (t < 2047) {
      size_t r1 = rbA + t + 1;
      if (T < 32)      gzA_p = (float)gzr[r1 * 1024 + c0 + T];
      else if (T < 64) grA_p = (float)gzr[r1 * 1024 + 512 + c0 + (T - 32)];
      ghA_p = (float)ghg[r1 * 512 + T];
    }
    {  // z/r GEMV A: thread (j,sub) covers K [sub*32, sub*32+32)
      float za = 0.f, ra = 0.f;
#pragma unroll
      for (int cc = 0; cc < 4; ++cc) {
        int kc = sub * 4 + cc;
        uint4 hu = *(const uint4*)&hA[kc * 8];                       // broadcast
        uint4 wz = *(const uint4*)&wzK[(kc * 32 + j) * 8];           // stride-16B
        uint4 wr = *(const uint4*)&wzK[((64 + kc) * 32 + j) * 8];
        za = dot2f(bc2(hu.x), bc2(wz.x), za); za = dot2f(bc2(hu.y), bc2(wz.y), za);
        za = dot2f(bc2(hu.z), bc2(wz.z), za); za = dot2f(bc2(hu.w), bc2(wz.w), za);
        ra = dot2f(bc2(hu.x), bc2(wr.x), ra); ra = dot2f(bc2(hu.y), bc2(wr.y), ra);
        ra = dot2f(bc2(hu.z), bc2(wr.z), ra); ra = dot2f(bc2(hu.w), bc2(wr.w), ra);
      }
      zrp[0][sub][j] = za;
      zrp[1][sub][j] = ra;
    }
    if (t > 0) {  // pre-issue B-combine (PB(t-1) published end of last iter)
      zvB = ald64(zrdB + zoC);
#pragma unroll
      for (int q = 0; q < 16; ++q) pvB[q] = ald32(PrB + poC + (size_t)q * 512);
    }
    __syncthreads();  // B2a: zrp ready
    if (T < 64) {
      const int g = T >> 5, jj = T & 31;
      float sum = 0.f;
#pragma unroll
      for (int q = 0; q < 16; ++q) sum += zrp[g][q][jj];
      if (g == 0) {
        float z = sigmoidf_(sum + gzA_c);
        ast64(zmA + zoN, ((uint64_t)tagN << 32) | (uint32_t)__float_as_uint(z));
      } else {
        float r = sigmoidf_(sum + grA_c);
        rhA[jj] = (_Float16)(r * (float)hA[c0 + jj]);
      }
    }
    __syncthreads();  // B3a: rhA ready
    {  // candidate A: P[T] = rh(own cols) @ Whh -> publish (coalesced)
      float pa = 0.f;
#pragma unroll
      for (int i = 0; i < 8; ++i) {
        uint2 ru = *(const uint2*)&rhA[4 * i];  // broadcast
        pa = dot2f(bc2(ru.x), bc2(wh2[2 * i]), pa);
        pa = dot2f(bc2(ru.y), bc2(wh2[2 * i + 1]), pa);
      }
      unsigned short pb = __builtin_bit_cast(unsigned short, (_Float16)pa);
      ast32(PmA + poN, (tagN << 16) | (uint32_t)pb);
    }

    // ================= B =================
    if (t > 0) {
      while (!tagsok(pvB, zvB, want)) {
        __builtin_amdgcn_s_sleep(1);
        zvB = ald64(zrdB + zoC);
#pragma unroll
        for (int q = 0; q < 16; ++q)
          if ((pvB[q] >> 16) != want) pvB[q] = ald32(PrB + poC + (size_t)q * 512);
      }
      float hsum = 0.f;
#pragma unroll
      for (int q = 0; q < 16; ++q) hsum += f16b2f(pvB[q]);
      float zf = __uint_as_float((uint32_t)zvB);
      float htil = tanhf_(ghB_c + hsum);
      float hn = fmaf(zf, htil - hregB, hregB);
      if (sub == s) out[(rbB + (t - 1)) * 512 + T] = hn;
      hregB = hn;
      hB[T] = (_Float16)hn;
    }
    gzB_c = gzB_p; grB_c = grB_p; ghB_c = ghB_p;
    __syncthreads();  // B1b
    if (t < 2047) {
      size_t r1 = rbB + t + 1;
      if (T < 32)      gzB_p = (float)gzr[r1 * 1024 + c0 + T];
      else if (T < 64) grB_p = (float)gzr[r1 * 1024 + 512 + c0 + (T - 32)];
      ghB_p = (float)ghg[r1 * 512 + T];
    }
    {  // z/r GEMV B
      float za = 0.f, ra = 0.f;
#pragma unroll
      for (int cc = 0; cc < 4; ++cc) {
        int kc = sub * 4 + cc;
        uint4 hu = *(const uint4*)&hB[kc * 8];
        uint4 wz = *(const uint4*)&wzK[(kc * 32 + j) * 8];
        uint4 wr = *(const uint4*)&wzK[((64 + kc) * 32 + j) * 8];
        za = dot2f(bc2(hu.x), bc2(wz.x), za); za = dot2f(bc2(hu.y), bc2(wz.y), za);
        za = dot2f(bc2(hu.z), bc2(wz.z), za); za = dot2f(bc2(hu.w), bc2(wz.w), za);
        ra = dot2f(bc2(hu.x), bc2(wr.x), ra); ra = dot2f(bc2(hu.y), bc2(wr.y), ra);
        ra = dot2f(bc2(hu.z), bc2(wr.z), ra); ra = dot2f(bc2(hu.w), bc2(wr.w), ra);
      }
      zrp[0][sub][j] = za;
      zrp[1][sub][j] = ra;
    }
    {  // pre-issue A-combine for next iter (PA(t) published just above)
      zvA = ald64(zrdA + zoN);
#pragma unroll
      for (int q = 0; q < 16; ++q) pvA[q] = ald32(PrA + poN + (size_t)q * 512);
    }
    __syncthreads();  // B2b
    if (T < 64) {
      const int g = T >> 5, jj = T & 31;
      float sum = 0.f;
#pragma unroll
      for (int q = 0; q < 16; ++q) sum += zrp[g][q][jj];
      if (g == 0) {
        float z = sigmoidf_(sum + gzB_c);
        ast64(zmB + zoN, ((uint64_t)tagN << 32) | (uint32_t)__float_as_uint(z));
      } else {
        float r = sigmoidf_(sum + grB_c);
        rhB[jj] = (_Float16)(r * (float)hB[c0 + jj]);
      }
    }
    __syncthreads();  // B3b
    {  // candidate B -> publish
      float pa = 0.f;
#pragma unroll
      for (int i = 0; i < 8; ++i) {
        uint2 ru = *(const uint2*)&rhB[4 * i];
        pa = dot2f(bc2(ru.x), bc2(wh2[2 * i]), pa);
        pa = dot2f(bc2(ru.y), bc2(wh2[2 * i + 1]), pa);
      }
      unsigned short pb = __builtin_bit_cast(unsigned short, (_Float16)pa);
      ast32(PmB + poN, (tagN << 16) | (uint32_t)pb);
    }
  }

  // ---- epilogue: combine step 2047 (parity 1, tag 2048) ----
  {
    const uint32_t want = 2048u;
    while (!tagsok(pvA, zvA, want)) {  // pvA pre-issued in final B-section
      __builtin_amdgcn_s_sleep(1);
      zvA = ald64(zrdA + 16384);
#pragma unroll
      for (int q = 0; q < 16; ++q)
        if ((pvA[q] >> 16) != want) pvA[q] = ald32(PrA + 262144 + (size_t)q * 512);
    }
    float hsum = 0.f;
#pragma unroll
    for (int q = 0; q < 16; ++q) hsum += f16b2f(pvA[q]);
    float zf = __uint_as_float((uint32_t)zvA);
    float htil = tanhf_(ghA_c + hsum);
    float hn = fmaf(zf, htil - hregA, hregA);
    if (sub == s) {
      out[(rbA + 2047) * 512 + T] = hn;
      out[(size_t)32 * 2048 * 512 + (size_t)bA * 512 + T] = hn;
    }
  }
  {
    const uint32_t want = 2048u;
    zvB = ald64(zrdB + 16384);
#pragma unroll
    for (int q = 0; q < 16; ++q) pvB[q] = ald32(PrB + 262144 + (size_t)q * 512);
    while (!tagsok(pvB, zvB, want)) {
      __builtin_amdgcn_s_sleep(1);
      zvB = ald64(zrdB + 16384);
#pragma unroll
      for (int q = 0; q < 16; ++q)
        if ((pvB[q] >> 16) != want) pvB[q] = ald32(PrB + 262144 + (size_t)q * 512);
    }
    float hsum = 0.f;
#pragma unroll
    for (int q = 0; q < 16; ++q) hsum += f16b2f(pvB[q]);
    float zf = __uint_as_float((uint32_t)zvB);
    float htil = tanhf_(ghB_c + hsum);
    float hn = fmaf(zf, htil - hregB, hregB);
    if (sub == s) {
      out[(rbB + 2047) * 512 + T] = hn;
      out[(size_t)32 * 2048 * 512 + (size_t)bB * 512 + T] = hn;
    }
  }
}

// ---------------- Fallback scan (R8 scalar, !gh_mode) ----------------
__global__ __launch_bounds__(512) void gru_scan_fb(
    const float* __restrict__ x, const float* __restrict__ Wx,
    const float* __restrict__ Wh, const float* __restrict__ bias,
    const _Float16* gzr, float* out,
    uint64_t* __restrict__ Pbuf, uint64_t* __restrict__ zbuf) {
  __shared__ alignas(16) float zrp[2][8][64];
  __shared__ alignas(16) _Float16 wzrL[2 * 64 * 516];
  __shared__ alignas(16) _Float16 h16[512];
  __shared__ alignas(16) _Float16 rh16[64];
  __shared__ alignas(16) _Float16 x16s[64];

  const int T = threadIdx.x;
  const int bid = blockIdx.x;
  const int xcd = bid & 7, ii = bid >> 3;
  const int batch = xcd * 4 + (ii >> 3);
  const int slice = ii & 7;
  const int wv = T >> 6, ln = T & 63, n = T;
  {
    const int cc = T & 63, kb = T >> 6;
#pragma unroll 4
    for (int g = 0; g < 2; ++g) {
      const float* W = Wh + (size_t)g * 262144 + slice * 64 + cc;
      for (int i = 0; i < 64; ++i) {
        int k = kb + 8 * i;
        wzrL[(g * 64 + cc) * 516 + k] = (_Float16)W[(size_t)k * 512];
      }
    }
  }
  uint32_t wh2[32], wx2[32];
  {
    const float* Whh = Wh + 524288;
    const float* Wxh = Wx + 524288;
#pragma unroll
    for (int jj = 0; jj < 32; ++jj) {
      int kk = slice * 64 + 2 * jj;
      wh2[jj] = pk2u(Whh[(size_t)kk * 512 + n], Whh[(size_t)(kk + 1) * 512 + n]);
      wx2[jj] = pk2u(Wxh[(size_t)kk * 512 + n], Wxh[(size_t)(kk + 1) * 512 + n]);
    }
  }
  const float bh = bias[1024 + n];
  float hreg = 0.0f;
  h16[T] = (_Float16)0.0f;
  const size_t rowbase = (size_t)batch * 2048;
  float gz_p = 0.f, gr_p = 0.f, gz_cur = 0.f, gr_cur = 0.f, x_p = 0.f;
  if (T < 64)       gz_p = (float)gzr[rowbase * 1024 + slice * 64 + T];
  else if (T < 128) gr_p = (float)gzr[rowbase * 1024 + 512 + slice * 64 + (T - 64)];
  if (T < 64) x_p = x[rowbase * 512 + slice * 64 + T];

  uint64_t* Pmine = Pbuf + ((size_t)batch * 8 + slice) * 512 + n;
  const uint64_t* Pread = Pbuf + ((size_t)batch * 8) * 512 + n;
  uint64_t* zmine = zbuf + (size_t)batch * 512 + slice * 64 + ln;
  const uint64_t* zread = zbuf + (size_t)batch * 512 + n;

  for (int t = 0; t < 2048; ++t) {
    if (t > 0) {
      const size_t po = ((t - 1) & 1) ? 131072 : 0;
      const size_t zo = ((t - 1) & 1) ? 16384 : 0;
      const uint32_t want = (uint32_t)t;
      uint64_t v[8];
#pragma unroll
      for (int g = 0; g < 8; ++g) v[g] = ald64(Pread + po + (size_t)g * 512);
      uint64_t zv = ald64(zread + zo);
      for (;;) {
        bool ok = true;
        if ((uint32_t)(zv >> 32) != want) { zv = ald64(zread + zo); ok = false; }
#pragma unroll
        for (int g = 0; g < 8; ++g)
          if ((uint32_t)(v[g] >> 32) != want) { v[g] = ald64(Pread + po + (size_t)g * 512); ok = false; }
        if (ok) break;
        __builtin_amdgcn_s_sleep(1);
      }
      float hsum = 0.f;
#pragma unroll
      for (int g = 0; g < 8; ++g) hsum += __uint_as_float((uint32_t)v[g]);
      float zf = __uint_as_float((uint32_t)zv);
      float htil = tanhf_(bh + hsum);
      float hn = fmaf(zf, htil - hreg, hreg);
      if (slice == 0) out[(rowbase + (t - 1)) * 512 + n] = hn;
      hreg = hn;
      h16[T] = (_Float16)hn;
    }
    gz_cur = gz_p; gr_cur = gr_p;
    if (T < 64) x16s[T] = (_Float16)x_p;
    __syncthreads();
    if (t < 2047) {
      size_t r1 = rowbase + t + 1;
      if (T < 64)       gz_p = (float)gzr[r1 * 1024 + slice * 64 + T];
      else if (T < 128) gr_p = (float)gzr[r1 * 1024 + 512 + slice * 64 + (T - 64)];
      if (T < 64) x_p = x[r1 * 512 + slice * 64 + T];
    }
    float za = 0.f, ra = 0.f;
    {
      const _Float16* wzp = &wzrL[ln * 516 + 64 * wv];
      const _Float16* wrp = &wzrL[(64 + ln) * 516 + 64 * wv];
      const _Float16* hp = &h16[64 * wv];
#pragma unroll
      for (int jj = 0; jj < 16; ++jj) {
        uint2 wzu = *(const uint2*)(wzp + 4 * jj);
        uint2 wru = *(const uint2*)(wrp + 4 * jj);
        uint2 hu = *(const uint2*)(hp + 4 * jj);
        za = dot2f(bc2(hu.x), bc2(wzu.x), za);
        za = dot2f(bc2(hu.y), bc2(wzu.y), za);
        ra = dot2f(bc2(hu.x), bc2(wru.x), ra);
        ra = dot2f(bc2(hu.y), bc2(wru.y), ra);
      }
    }
    zrp[0][wv][ln] = za;
    zrp[1][wv][ln] = ra;
    __syncthreads();
    const size_t po = (t & 1) ? 131072 : 0;
    const size_t zo = (t & 1) ? 16384 : 0;
    const uint64_t tagw = ((uint64_t)(uint32_t)(t + 1)) << 32;
    if (T < 128) {
      const int g = T >> 6, cc = T & 63;
      float sum = 0.f;
#pragma unroll
      for (int s2 = 0; s2 < 8; ++s2) sum += zrp[g][s2][cc];
      if (g == 0) {
        float z = sigmoidf_(sum + gz_cur);
        ast64(zmine + zo, tagw | (uint32_t)__float_as_uint(z));
      } else {
        float r = sigmoidf_(sum + gr_cur);
        rh16[cc] = (_Float16)(r * (float)h16[slice * 64 + cc]);
      }
    }
    __syncthreads();
    float pa = 0.f;
#pragma unroll
    for (int jj = 0; jj < 16; ++jj) {
      uint2 ru = *(const uint2*)&rh16[4 * jj];
      pa = dot2f(bc2(ru.x), bc2(wh2[2 * jj]), pa);
      pa = dot2f(bc2(ru.y), bc2(wh2[2 * jj + 1]), pa);
    }
#pragma unroll
    for (int jj = 0; jj < 16; ++jj) {
      uint2 xu = *(const uint2*)&x16s[4 * jj];
      pa = dot2f(bc2(xu.x), bc2(wx2[2 * jj]), pa);
      pa = dot2f(bc2(xu.y), bc2(wx2[2 * jj + 1]), pa);
    }
    ast64(Pmine + po, tagw | (uint32_t)__float_as_uint(pa));
    __syncthreads();
  }
  {
    const uint32_t want = 2048u;
    uint64_t v[8];
#pragma unroll
    for (int g = 0; g < 8; ++g) v[g] = ald64(Pread + 131072 + (size_t)g * 512);
    uint64_t zv = ald64(zread + 16384);
    for (;;) {
      bool ok = true;
      if ((uint32_t)(zv >> 32) != want) { zv = ald64(zread + 16384); ok = false; }
#pragma unroll
      for (int g = 0; g < 8; ++g)
        if ((uint32_t)(v[g] >> 32) != want) { v[g] = ald64(Pread + 131072 + (size_t)g * 512); ok = false; }
      if (ok) break;
      __builtin_amdgcn_s_sleep(1);
    }
    float hsum = 0.f;
#pragma unroll
    for (int g = 0; g < 8; ++g) hsum += __uint_as_float((uint32_t)v[g]);
    float zf = __uint_as_float((uint32_t)zv);
    float htil = tanhf_(bh + hsum);
    float hn = fmaf(zf, htil - hreg, hreg);
    if (slice == 0) {
      out[(rowbase + 2047) * 512 + n] = hn;
      out[(size_t)32 * 2048 * 512 + (size_t)batch * 512 + n] = hn;
    }
  }
}

extern "C" void kernel_launch(void* const* d_in, const int* in_sizes, int n_in,
                              void* d_out, int out_size, void* d_ws, size_t ws_size,
                              hipStream_t stream) {
  (void)in_sizes; (void)n_in; (void)out_size;
  const float* x    = (const float*)d_in[0];
  const float* Wx   = (const float*)d_in[1];
  const float* Wh   = (const float*)d_in[2];
  const float* bias = (const float*)d_in[3];
  float* out = (float*)d_out;
  char* ws = (char*)d_ws;

  // gh_mode layout: Pbuf u32 [2][32][16][512] = 2 MB | zbuf u64 [2][32][512] = 256 KB | gh @ 2621440
  // fallback layout: Pbuf u64 2 MB | zbuf u64 @ 2097152
  uint32_t* Pbuf2 = (uint32_t*)ws;
  uint64_t* zbuf2 = (uint64_t*)(ws + 2097152);
  uint64_t* PbufF = (uint64_t*)ws;
  uint64_t* zbufF = (uint64_t*)(ws + 2097152);
  _Float16* gh    = (_Float16*)(ws + 2621440);

  hipMemsetAsync(ws, 0, 2621440, stream);  // reset exchange tags (replay-safe)
  const bool gh_mode = ws_size >= (size_t)2621440 + 67108864ull;
  if (gh_mode) {
    gemm_gx<<<512 * 12, 256, 0, stream>>>(x, Wx, bias, (_Float16*)d_out, gh, 12);
    gru_scan2<<<256, 512, 0, stream>>>((const _Float16*)d_out, gh, Wh, out,
                                       Pbuf2, zbuf2);
  } else {
    gemm_gx<<<512 * 8, 256, 0, stream>>>(x, Wx, bias, (_Float16*)d_out, gh, 8);
    gru_scan_fb<<<256, 512, 0, stream>>>(x, Wx, Wh, bias, (const _Float16*)d_out,
                                         out, PbufF, zbufF);
  }
}